// Round 3
// baseline (1453.287 us; speedup 1.0000x reference)
//
#include <hip/hip_runtime.h>
#include <cstdint>
#include <cstddef>

typedef unsigned short u16;
typedef short bf16x8 __attribute__((ext_vector_type(8)));
typedef float f32x4 __attribute__((ext_vector_type(4)));

__device__ __forceinline__ u16 f2bf(float f) {
  unsigned u = __float_as_uint(f);
  u += 0x7fffu + ((u >> 16) & 1u);   // round-to-nearest-even
  return (u16)(u >> 16);
}

// ------- prep: x -> bf16, proj0 = x@tp0 [2048][128], proj1 = x@tp1 [2048][32] -------
// one block per token row; also emits x_bf (merged former cast_x kernel)
__global__ __launch_bounds__(256) void proj_kernel(const float* __restrict__ x,
                                                   const float* __restrict__ tp0,
                                                   const float* __restrict__ tp1,
                                                   u16* __restrict__ xb,
                                                   u16* __restrict__ p0,
                                                   u16* __restrict__ p1) {
  __shared__ float xr[512];
  const int t = blockIdx.x;
  const int j = threadIdx.x;
  {  // load row, stash to LDS, and write bf16 copy (2 elems/thread)
    float2 v = ((const float2*)(x + (size_t)t * 512))[j];
    xr[2 * j] = v.x;
    xr[2 * j + 1] = v.y;
    ushort2 o;
    o.x = f2bf(v.x);
    o.y = f2bf(v.y);
    ((ushort2*)(xb + (size_t)t * 512))[j] = o;
  }
  __syncthreads();
  if (j < 128) {
    float a = 0.f;
    for (int h = 0; h < 512; ++h) a += xr[h] * tp0[h * 128 + j];
    p0[t * 128 + j] = f2bf(a);
  } else if (j < 160) {
    const int j2 = j - 128;
    float a = 0.f;
    for (int h = 0; h < 512; ++h) a += xr[h] * tp1[h * 32 + j2];
    p1[t * 32 + j2] = f2bf(a);
  }
}

// ------- prep: W[K][V] f32 -> Wt[Vpad][K] bf16 (transpose + cast, zero-padded) -------
__global__ __launch_bounds__(256) void transpose_cast_kernel(const float* __restrict__ W,
                                                             u16* __restrict__ Wt,
                                                             int K, int V, int Vpad) {
  __shared__ float tile[64][65];
  const int v0 = blockIdx.x * 64, k0 = blockIdx.y * 64;
  for (int l = threadIdx.x; l < 4096; l += 256) {
    int kl = l >> 6, vl = l & 63;
    int kg = k0 + kl, vg = v0 + vl;
    tile[kl][vl] = (kg < K && vg < V) ? W[(size_t)kg * V + vg] : 0.f;
  }
  __syncthreads();
  for (int l = threadIdx.x; l < 4096; l += 256) {
    int vl = l >> 6, kl = l & 63;
    int vg = v0 + vl, kg = k0 + kl;
    if (vg < Vpad && kg < K) Wt[(size_t)vg * K + kg] = f2bf(tile[kl][vl]);
  }
}

// ---------------- zero the atomic accumulators (ws is poisoned 0xAA) ----------------
__global__ __launch_bounds__(256) void zero_kernel(float* __restrict__ p, int n) {
  int i = blockIdx.x * 256 + threadIdx.x;
  if (i < n) p[i] = 0.f;
}

// ---------------- GEMM passes ----------------
// MODE 0: pass1 head  (sum exp -> atomics; store cluster logits at cols 20000/20001)
// MODE 1: pass1 tail  (sum exp -> atomics)
// MODE 2: pass2 head  (write exp(l)*fac for cols < 20000)
// MODE 3: pass2 tail  (write exp(l)*fac for cols < V)
// 128x128 tile, BK=32, 256 thr = 4 waves, each wave a 32-row band x 128 cols.
// No max-subtraction needed: logit sigma ~0.45, |logit| <~ 3 -> exp safe in fp32.
template <int K, int MODE>
__global__ __launch_bounds__(256) void gemm_pass(const u16* __restrict__ A,
                                                 const u16* __restrict__ Wt,
                                                 float* __restrict__ out,
                                                 float* __restrict__ clus,
                                                 float* __restrict__ sums,
                                                 const float* __restrict__ fac,
                                                 int V, int outColOff, int secIdx) {
  constexpr int LDT = 40;   // 32 + 8 pad: 80B stride -> b128 reads hit 8/bank (optimal)
  __shared__ __align__(16) u16 As[128 * LDT];
  __shared__ __align__(16) u16 Bs[128 * LDT];
  const int tid = threadIdx.x;
  const int lane = tid & 63, wave = tid >> 6;
  const int t0 = blockIdx.y * 128;
  const int v0 = blockIdx.x * 128;

  f32x4 acc[2][8];
#pragma unroll
  for (int i = 0; i < 2; ++i)
#pragma unroll
    for (int j = 0; j < 8; ++j) acc[i][j] = (f32x4){0.f, 0.f, 0.f, 0.f};

  const int rl = lane & 15;
  const int kb = (lane >> 4) * 8;   // k-base of this lane's fragment slice

  for (int kk = 0; kk < K; kk += 32) {
    // stage A[128][32] and Wt[128][32] (row-major, one uint4 per thread per matrix)
#pragma unroll
    for (int c0 = 0; c0 < 2; ++c0) {
      int c = c0 * 256 + tid;
      int r = c >> 2, kc = c & 3;
      *(uint4*)&As[r * LDT + kc * 8] =
          *(const uint4*)&A[(size_t)(t0 + r) * K + kk + kc * 8];
      *(uint4*)&Bs[r * LDT + kc * 8] =
          *(const uint4*)&Wt[(size_t)(v0 + r) * K + kk + kc * 8];
    }
    __syncthreads();

    bf16x8 fa[2], fb[8];
#pragma unroll
    for (int rf = 0; rf < 2; ++rf)
      fa[rf] = *(const bf16x8*)&As[(wave * 32 + rf * 16 + rl) * LDT + kb];
#pragma unroll
    for (int cf = 0; cf < 8; ++cf)
      fb[cf] = *(const bf16x8*)&Bs[(cf * 16 + rl) * LDT + kb];
#pragma unroll
    for (int rf = 0; rf < 2; ++rf)
#pragma unroll
      for (int cf = 0; cf < 8; ++cf)
        acc[rf][cf] =
            __builtin_amdgcn_mfma_f32_16x16x32_bf16(fa[rf], fb[cf], acc[rf][cf], 0, 0, 0);
    __syncthreads();
  }

  // epilogue: C/D layout col=lane&15, row=(lane>>4)*4+reg  [m89-verified]
  const int rbase = (lane >> 4) * 4;

  if (MODE <= 1) {
    // ---- pass 1: per-token sum of exp(logit), atomically merged ----
#pragma unroll
    for (int rf = 0; rf < 2; ++rf) {
#pragma unroll
      for (int r = 0; r < 4; ++r) {
        const int tok = t0 + wave * 32 + rf * 16 + rbase + r;
        float s = 0.f;
#pragma unroll
        for (int cf = 0; cf < 8; ++cf) {
          const int colv = v0 + cf * 16 + rl;
          const float l = acc[rf][cf][r];
          const float e = __expf(l);
          s += (colv < V) ? e : 0.f;   // Vpad cols are zero-logit -> excluded
          if (MODE == 0) {
            if (colv >= 20000 && colv < V) clus[tok * 2 + (colv - 20000)] = l;
          }
        }
        // reduce across the 16 column-lanes holding the same token
#pragma unroll
        for (int m = 1; m < 16; m <<= 1) s += __shfl_xor(s, m, 64);
        if (rl == 0) atomicAdd(&sums[tok * 3 + secIdx], s);
      }
    }
  } else {
    // ---- pass 2: write exp(logit) * per-token factor (streaming, non-temporal) ----
    const int lim = (MODE == 2) ? 20000 : V;
#pragma unroll
    for (int rf = 0; rf < 2; ++rf) {
#pragma unroll
      for (int r = 0; r < 4; ++r) {
        const int tok = t0 + wave * 32 + rf * 16 + rbase + r;
        const float f = fac[tok * 3 + secIdx];
        float* orow = out + (size_t)tok * 100000 + outColOff + v0;
#pragma unroll
        for (int cf = 0; cf < 8; ++cf) {
          const int colv = v0 + cf * 16 + rl;
          if (colv < lim)
            __builtin_nontemporal_store(__expf(acc[rf][cf][r]) * f,
                                        orow + cf * 16 + rl);
        }
      }
    }
  }
}

// ---------------- per-token factor per section ----------------
__global__ void factors_kernel(const float* __restrict__ sums,
                               const float* __restrict__ clus,
                               float* __restrict__ fac) {
  int t = blockIdx.x * blockDim.x + threadIdx.x;
  if (t >= 2048) return;
  float inv_sh = 1.f / sums[t * 3 + 0];
  fac[t * 3 + 0] = inv_sh;
  float cp0 = __expf(clus[t * 2 + 0]) * inv_sh;   // cluster probs (|logit| small,
  float cp1 = __expf(clus[t * 2 + 1]) * inv_sh;   // no max subtraction needed)
  fac[t * 3 + 1] = cp0 / sums[t * 3 + 1];
  fac[t * 3 + 2] = cp1 / sums[t * 3 + 2];
}

extern "C" void kernel_launch(void* const* d_in, const int* in_sizes, int n_in,
                              void* d_out, int out_size, void* d_ws, size_t ws_size,
                              hipStream_t stream) {
  const float* x   = (const float*)d_in[0];   // [2,1024,512]
  const float* hw  = (const float*)d_in[1];   // [512,20002]
  const float* tp0 = (const float*)d_in[2];   // [512,128]
  const float* tw0 = (const float*)d_in[3];   // [128,30000]
  const float* tp1 = (const float*)d_in[4];   // [512,32]
  const float* tw1 = (const float*)d_in[5];   // [32,50000]
  float* out = (float*)d_out;
  char* ws = (char*)d_ws;

  // ws layout (bytes), total ~34.3 MB, all 16B-aligned
  u16* wt_h    = (u16*)(ws + 0);          // 20096*512*2  = 20578304
  u16* wt_t0   = (u16*)(ws + 20578304);   // 30080*128*2  =  7700480
  u16* wt_t1   = (u16*)(ws + 28278784);   // 50048*32*2   =  3203072
  u16* x_bf    = (u16*)(ws + 31481856);   // 2048*512*2   =  2097152
  u16* p0_bf   = (u16*)(ws + 33579008);   // 2048*128*2   =   524288
  u16* p1_bf   = (u16*)(ws + 34103296);   // 2048*32*2    =   131072
  float* clus  = (float*)(ws + 34234368); // 2048*2*4     =    16384
  float* sums  = (float*)(ws + 34250752); // 2048*3*4     =    24576
  float* fac   = (float*)(ws + 34275328); // 2048*3*4     =    24576

  // prep
  zero_kernel<<<24, 256, 0, stream>>>(sums, 2048 * 3);
  proj_kernel<<<2048, 256, 0, stream>>>(x, tp0, tp1, x_bf, p0_bf, p1_bf);
  transpose_cast_kernel<<<dim3(314, 8), 256, 0, stream>>>(hw,  wt_h,  512, 20002, 20096);
  transpose_cast_kernel<<<dim3(470, 2), 256, 0, stream>>>(tw0, wt_t0, 128, 30000, 30080);
  transpose_cast_kernel<<<dim3(782, 1), 256, 0, stream>>>(tw1, wt_t1, 32,  50000, 50048);

  // pass 1: sum-exp stats (no logit materialization)
  gemm_pass<512, 0><<<dim3(157, 16), 256, 0, stream>>>(x_bf,  wt_h,  nullptr, clus, sums, nullptr, 20002, 0, 0);
  gemm_pass<128, 1><<<dim3(235, 16), 256, 0, stream>>>(p0_bf, wt_t0, nullptr, nullptr, sums, nullptr, 30000, 0, 1);
  gemm_pass<32,  1><<<dim3(391, 16), 256, 0, stream>>>(p1_bf, wt_t1, nullptr, nullptr, sums, nullptr, 50000, 0, 2);

  factors_kernel<<<8, 256, 0, stream>>>(sums, clus, fac);

  // pass 2: recompute logits, write normalized probabilities directly
  gemm_pass<512, 2><<<dim3(157, 16), 256, 0, stream>>>(x_bf,  wt_h,  out, nullptr, nullptr, fac, 20002, 0, 0);
  gemm_pass<128, 3><<<dim3(235, 16), 256, 0, stream>>>(p0_bf, wt_t0, out, nullptr, nullptr, fac, 30000, 20000, 1);
  gemm_pass<32,  3><<<dim3(391, 16), 256, 0, stream>>>(p1_bf, wt_t1, out, nullptr, nullptr, fac, 50000, 50000, 2);
}

// Round 4
// 1434.777 us; speedup vs baseline: 1.0129x; 1.0129x over previous
//
#include <hip/hip_runtime.h>
#include <cstdint>
#include <cstddef>

typedef unsigned short u16;
typedef short bf16x8 __attribute__((ext_vector_type(8)));
typedef float f32x4 __attribute__((ext_vector_type(4)));

__device__ __forceinline__ u16 f2bf(float f) {
  unsigned u = __float_as_uint(f);
  u += 0x7fffu + ((u >> 16) & 1u);   // round-to-nearest-even
  return (u16)(u >> 16);
}

// async 16B global -> LDS (linear dest: wave-uniform base + lane*16)
__device__ __forceinline__ void gload_lds16(const u16* g, u16* l) {
  __builtin_amdgcn_global_load_lds(
      (const __attribute__((address_space(1))) void*)g,
      (__attribute__((address_space(3))) void*)l, 16, 0, 0);
}

// ------- prep: x -> bf16, proj0 = x@tp0 [2048][128], proj1 = x@tp1 [2048][32] -------
__global__ __launch_bounds__(256) void proj_kernel(const float* __restrict__ x,
                                                   const float* __restrict__ tp0,
                                                   const float* __restrict__ tp1,
                                                   u16* __restrict__ xb,
                                                   u16* __restrict__ p0,
                                                   u16* __restrict__ p1) {
  __shared__ float xr[512];
  const int t = blockIdx.x;
  const int j = threadIdx.x;
  {
    float2 v = ((const float2*)(x + (size_t)t * 512))[j];
    xr[2 * j] = v.x;
    xr[2 * j + 1] = v.y;
    ushort2 o;
    o.x = f2bf(v.x);
    o.y = f2bf(v.y);
    ((ushort2*)(xb + (size_t)t * 512))[j] = o;
  }
  __syncthreads();
  if (j < 128) {
    float a = 0.f;
    for (int h = 0; h < 512; ++h) a += xr[h] * tp0[h * 128 + j];
    p0[t * 128 + j] = f2bf(a);
  } else if (j < 160) {
    const int j2 = j - 128;
    float a = 0.f;
    for (int h = 0; h < 512; ++h) a += xr[h] * tp1[h * 32 + j2];
    p1[t * 32 + j2] = f2bf(a);
  }
}

// ------- prep: W[K][V] f32 -> Wt[Vpad][K] bf16 (transpose + cast, zero-padded) -------
__global__ __launch_bounds__(256) void transpose_cast_kernel(const float* __restrict__ W,
                                                             u16* __restrict__ Wt,
                                                             int K, int V, int Vpad) {
  __shared__ float tile[64][65];
  const int v0 = blockIdx.x * 64, k0 = blockIdx.y * 64;
  for (int l = threadIdx.x; l < 4096; l += 256) {
    int kl = l >> 6, vl = l & 63;
    int kg = k0 + kl, vg = v0 + vl;
    tile[kl][vl] = (kg < K && vg < V) ? W[(size_t)kg * V + vg] : 0.f;
  }
  __syncthreads();
  for (int l = threadIdx.x; l < 4096; l += 256) {
    int vl = l >> 6, kl = l & 63;
    int vg = v0 + vl, kg = k0 + kl;
    if (vg < Vpad && kg < K) Wt[(size_t)vg * K + kg] = f2bf(tile[kl][vl]);
  }
}

// ---------------- zero the atomic accumulators (ws is poisoned 0xAA) ----------------
__global__ __launch_bounds__(256) void zero_kernel(float* __restrict__ p, int n) {
  int i = blockIdx.x * 256 + threadIdx.x;
  if (i < n) p[i] = 0.f;
}

// ================= shared epilogue =================
// C/D layout col=lane&15, row=(lane>>4)*4+reg  [m89-verified]
// MODE 0: pass1 head (sum exp -> atomics; cluster logits at cols 20000/20001)
// MODE 1: pass1 tail (sum exp -> atomics)
// MODE 2: pass2 head (write exp(l)*fac, cols < 20000)
// MODE 3: pass2 tail (write exp(l)*fac, cols < V)
template <int MODE>
__device__ __forceinline__ void epilogue(f32x4 (&acc)[2][8], int lane, int wave,
                                         int t0, int v0, float* __restrict__ out,
                                         float* __restrict__ clus,
                                         float* __restrict__ sums,
                                         const float* __restrict__ fac,
                                         int V, int outColOff, int secIdx) {
  const int rl = lane & 15;
  const int rbase = (lane >> 4) * 4;
  if (MODE <= 1) {
#pragma unroll
    for (int rf = 0; rf < 2; ++rf) {
#pragma unroll
      for (int r = 0; r < 4; ++r) {
        const int tok = t0 + wave * 32 + rf * 16 + rbase + r;
        float s = 0.f;
#pragma unroll
        for (int cf = 0; cf < 8; ++cf) {
          const int colv = v0 + cf * 16 + rl;
          const float l = acc[rf][cf][r];
          s += (colv < V) ? __expf(l) : 0.f;   // pad cols excluded
          if (MODE == 0) {
            if (colv >= 20000 && colv < V) clus[tok * 2 + (colv - 20000)] = l;
          }
        }
#pragma unroll
        for (int m = 1; m < 16; m <<= 1) s += __shfl_xor(s, m, 64);
        if (rl == 0) atomicAdd(&sums[tok * 3 + secIdx], s);
      }
    }
  } else {
    const int lim = (MODE == 2) ? 20000 : V;
#pragma unroll
    for (int rf = 0; rf < 2; ++rf) {
#pragma unroll
      for (int r = 0; r < 4; ++r) {
        const int tok = t0 + wave * 32 + rf * 16 + rbase + r;
        const float f = fac[tok * 3 + secIdx];
        float* orow = out + (size_t)tok * 100000 + outColOff + v0;
#pragma unroll
        for (int cf = 0; cf < 8; ++cf) {
          const int colv = v0 + cf * 16 + rl;
          if (colv < lim) orow[cf * 16 + rl] = __expf(acc[rf][cf][r]) * f;
        }
      }
    }
  }
}

// ================= m97-style GEMM (global_load_lds, linear LDS) =================
// 128x128 tile, BK=32, 256 thr = 4 waves; wave w owns rows [32w,32w+32) x 128 cols.
template <int K, int MODE>
__global__ __launch_bounds__(256) void gemm_pass(const u16* __restrict__ A,
                                                 const u16* __restrict__ Wt,
                                                 float* __restrict__ out,
                                                 float* __restrict__ clus,
                                                 float* __restrict__ sums,
                                                 const float* __restrict__ fac,
                                                 int V, int outColOff, int secIdx) {
  __shared__ __align__(16) u16 As[128 * 32];   // linear: row stride 32 shorts (64B)
  __shared__ __align__(16) u16 Bs[128 * 32];
  const int tid = threadIdx.x;
  const int lane = tid & 63, wave = tid >> 6;
  const int t0 = blockIdx.y * 128;
  const int v0 = blockIdx.x * 128;

  f32x4 acc[2][8];
#pragma unroll
  for (int i = 0; i < 2; ++i)
#pragma unroll
    for (int j = 0; j < 8; ++j) acc[i][j] = (f32x4){0.f, 0.f, 0.f, 0.f};

  const int rl = lane & 15;
  const int kb = (lane >> 4) * 8;

  // per-lane staging geometry: chunk = 1KB = 16 rows x 32 shorts
  const int crow = lane >> 2;          // 0..15 row within chunk
  const int ccol = (lane & 3) * 8;     // 0,8,16,24 shorts

  for (int kk = 0; kk < K; kk += 32) {
    // wave w stages chunks 2w and 2w+1 of both A and B (8 chunks each, 16 rows/chunk)
#pragma unroll
    for (int i = 0; i < 2; ++i) {
      const int c = wave * 2 + i;
      const int row = c * 16 + crow;
      gload_lds16(&A[(size_t)(t0 + row) * K + kk + ccol], &As[c * 512]);
      gload_lds16(&Wt[(size_t)(v0 + row) * K + kk + ccol], &Bs[c * 512]);
    }
    __syncthreads();   // drains vmcnt(0) -> LDS valid

    bf16x8 fa[2], fb[8];
#pragma unroll
    for (int rf = 0; rf < 2; ++rf)
      fa[rf] = *(const bf16x8*)&As[(wave * 32 + rf * 16 + rl) * 32 + kb];
#pragma unroll
    for (int cf = 0; cf < 8; ++cf)
      fb[cf] = *(const bf16x8*)&Bs[(cf * 16 + rl) * 32 + kb];
#pragma unroll
    for (int rf = 0; rf < 2; ++rf)
#pragma unroll
      for (int cf = 0; cf < 8; ++cf)
        acc[rf][cf] =
            __builtin_amdgcn_mfma_f32_16x16x32_bf16(fa[rf], fb[cf], acc[rf][cf], 0, 0, 0);
    __syncthreads();
  }

  epilogue<MODE>(acc, lane, wave, t0, v0, out, clus, sums, fac, V, outColOff, secIdx);
}

// ================= K=32 tiny GEMM: no LDS, fragments direct from global =================
// b128 per lane; a 16-lane group's 4 k-slices cover 16 full 64B rows -> coalesced 1KB.
template <int MODE>
__global__ __launch_bounds__(256) void gemm_tiny(const u16* __restrict__ A,
                                                 const u16* __restrict__ Wt,
                                                 float* __restrict__ out,
                                                 float* __restrict__ clus,
                                                 float* __restrict__ sums,
                                                 const float* __restrict__ fac,
                                                 int V, int outColOff, int secIdx) {
  const int tid = threadIdx.x;
  const int lane = tid & 63, wave = tid >> 6;
  const int t0 = blockIdx.y * 128;
  const int v0 = blockIdx.x * 128;
  const int rl = lane & 15;
  const int kb = (lane >> 4) * 8;

  f32x4 acc[2][8];
#pragma unroll
  for (int i = 0; i < 2; ++i)
#pragma unroll
    for (int j = 0; j < 8; ++j) acc[i][j] = (f32x4){0.f, 0.f, 0.f, 0.f};

  bf16x8 fa[2], fb[8];
#pragma unroll
  for (int rf = 0; rf < 2; ++rf)
    fa[rf] = *(const bf16x8*)&A[(size_t)(t0 + wave * 32 + rf * 16 + rl) * 32 + kb];
#pragma unroll
  for (int cf = 0; cf < 8; ++cf)
    fb[cf] = *(const bf16x8*)&Wt[(size_t)(v0 + cf * 16 + rl) * 32 + kb];
#pragma unroll
  for (int rf = 0; rf < 2; ++rf)
#pragma unroll
    for (int cf = 0; cf < 8; ++cf)
      acc[rf][cf] =
          __builtin_amdgcn_mfma_f32_16x16x32_bf16(fa[rf], fb[cf], acc[rf][cf], 0, 0, 0);

  epilogue<MODE>(acc, lane, wave, t0, v0, out, clus, sums, fac, V, outColOff, secIdx);
}

// ---------------- per-token factor per section ----------------
__global__ void factors_kernel(const float* __restrict__ sums,
                               const float* __restrict__ clus,
                               float* __restrict__ fac) {
  int t = blockIdx.x * blockDim.x + threadIdx.x;
  if (t >= 2048) return;
  float inv_sh = 1.f / sums[t * 3 + 0];
  fac[t * 3 + 0] = inv_sh;
  float cp0 = __expf(clus[t * 2 + 0]) * inv_sh;
  float cp1 = __expf(clus[t * 2 + 1]) * inv_sh;
  fac[t * 3 + 1] = cp0 / sums[t * 3 + 1];
  fac[t * 3 + 2] = cp1 / sums[t * 3 + 2];
}

extern "C" void kernel_launch(void* const* d_in, const int* in_sizes, int n_in,
                              void* d_out, int out_size, void* d_ws, size_t ws_size,
                              hipStream_t stream) {
  const float* x   = (const float*)d_in[0];   // [2,1024,512]
  const float* hw  = (const float*)d_in[1];   // [512,20002]
  const float* tp0 = (const float*)d_in[2];   // [512,128]
  const float* tw0 = (const float*)d_in[3];   // [128,30000]
  const float* tp1 = (const float*)d_in[4];   // [512,32]
  const float* tw1 = (const float*)d_in[5];   // [32,50000]
  float* out = (float*)d_out;
  char* ws = (char*)d_ws;

  u16* wt_h    = (u16*)(ws + 0);          // 20096*512*2  = 20578304
  u16* wt_t0   = (u16*)(ws + 20578304);   // 30080*128*2  =  7700480
  u16* wt_t1   = (u16*)(ws + 28278784);   // 50048*32*2   =  3203072
  u16* x_bf    = (u16*)(ws + 31481856);   // 2048*512*2   =  2097152
  u16* p0_bf   = (u16*)(ws + 33579008);   // 2048*128*2   =   524288
  u16* p1_bf   = (u16*)(ws + 34103296);   // 2048*32*2    =   131072
  float* clus  = (float*)(ws + 34234368); // 2048*2*4
  float* sums  = (float*)(ws + 34250752); // 2048*3*4
  float* fac   = (float*)(ws + 34275328); // 2048*3*4

  // prep
  zero_kernel<<<24, 256, 0, stream>>>(sums, 2048 * 3);
  proj_kernel<<<2048, 256, 0, stream>>>(x, tp0, tp1, x_bf, p0_bf, p1_bf);
  transpose_cast_kernel<<<dim3(314, 8), 256, 0, stream>>>(hw,  wt_h,  512, 20002, 20096);
  transpose_cast_kernel<<<dim3(470, 2), 256, 0, stream>>>(tw0, wt_t0, 128, 30000, 30080);
  transpose_cast_kernel<<<dim3(782, 1), 256, 0, stream>>>(tw1, wt_t1, 32,  50000, 50048);

  // pass 1: sum-exp stats (no logit materialization)
  gemm_pass<512, 0><<<dim3(157, 16), 256, 0, stream>>>(x_bf,  wt_h,  nullptr, clus, sums, nullptr, 20002, 0, 0);
  gemm_pass<128, 1><<<dim3(235, 16), 256, 0, stream>>>(p0_bf, wt_t0, nullptr, nullptr, sums, nullptr, 30000, 0, 1);
  gemm_tiny<1><<<dim3(391, 16), 256, 0, stream>>>(p1_bf, wt_t1, nullptr, nullptr, sums, nullptr, 50000, 0, 2);

  factors_kernel<<<8, 256, 0, stream>>>(sums, clus, fac);

  // pass 2: recompute logits, write normalized probabilities directly
  gemm_pass<512, 2><<<dim3(157, 16), 256, 0, stream>>>(x_bf,  wt_h,  out, nullptr, nullptr, fac, 20002, 0, 0);
  gemm_pass<128, 3><<<dim3(235, 16), 256, 0, stream>>>(p0_bf, wt_t0, out, nullptr, nullptr, fac, 30000, 20000, 1);
  gemm_tiny<3><<<dim3(391, 16), 256, 0, stream>>>(p1_bf, wt_t1, out, nullptr, nullptr, fac, 50000, 50000, 2);
}